// Round 3
// baseline (1204.549 us; speedup 1.0000x reference)
//
#include <hip/hip_runtime.h>
#include <cmath>

#define HID 128

typedef __attribute__((ext_vector_type(8))) short bf16x8;
typedef __attribute__((ext_vector_type(4))) float f32x4;

__device__ __forceinline__ unsigned short f2bf(float f) {
    union { float f; unsigned int i; } c; c.f = f;
    unsigned int r = c.i + 0x7fffu + ((c.i >> 16) & 1u);
    return (unsigned short)(r >> 16);
}
__device__ __forceinline__ unsigned cvt_pk(float lo, float hi) {
    unsigned r;
    asm("v_cvt_pk_bf16_f32 %0, %1, %2" : "=v"(r) : "v"(lo), "v"(hi));
    return r;
}
__device__ __forceinline__ float silu_f(float v) {
    float t = __builtin_amdgcn_exp2f(-1.44269504f * v);
    return v * __builtin_amdgcn_rcpf(1.0f + t);
}
__device__ __forceinline__ float sigmoid_f(float v) {
    return __builtin_amdgcn_rcpf(1.0f + __builtin_amdgcn_exp2f(-1.44269504f * v));
}

// ---------------------------------------------------------------------------
// Weight prep: A-fragments of W^T. For output-feature tile nt, k-chunk kc:
//   dst[((nt*KC + kc)*64 + lane)*8 + j] = W[k][nt*16 + (lane&15)]
//   k = kc*32 + (lane>>4)*4 + (j&3) + 16*(j>>2)
// frags: 0..63 We1p(KC=8) | 64..95 We2p | 96..127 Wc1p | 128..191 Wn1p(KC=8) | 192..223 Wn2p
// ---------------------------------------------------------------------------
__global__ __launch_bounds__(256) void egnn_prep(
    const float* __restrict__ We1, const float* __restrict__ We2,
    const float* __restrict__ Wc1, const float* __restrict__ Wn1,
    const float* __restrict__ Wn2,
    short* __restrict__ We1p, short* __restrict__ We2p, short* __restrict__ Wc1p,
    short* __restrict__ Wn1p, short* __restrict__ Wn2p)
{
    int t = blockIdx.x * 256 + threadIdx.x;
    int frag = t >> 6, lane = t & 63;
    if (frag >= 224) return;
    const float* W; short* dst; int KC, f;
    if (frag < 64)       { W = We1; dst = We1p; KC = 8; f = frag; }
    else if (frag < 96)  { W = We2; dst = We2p; KC = 4; f = frag - 64; }
    else if (frag < 128) { W = Wc1; dst = Wc1p; KC = 4; f = frag - 96; }
    else if (frag < 192) { W = Wn1; dst = Wn1p; KC = 8; f = frag - 128; }
    else                 { W = Wn2; dst = Wn2p; KC = 4; f = frag - 192; }
    int nt = f / KC, kc = f % KC;
    int n = nt * 16 + (lane & 15);
    short* d = dst + (((size_t)nt * KC + kc) * 64 + lane) * 8;
    #pragma unroll
    for (int j = 0; j < 8; ++j) {
        int k = kc * 32 + ((lane >> 4) << 2) + (j & 3) + ((j >> 2) << 4);
        d[j] = (short)f2bf(W[(size_t)k * HID + n]);
    }
}

// ---------------------------------------------------------------------------
// Edge kernel: 64 edges/block, 4 waves; wave w owns edges w*16+l15 (N-dim),
// all 128 output features (M-dim, 8 row-frags). Layers chain in-register.
// ---------------------------------------------------------------------------
__global__ __launch_bounds__(256) void egnn_edge_mfma(
    const float* __restrict__ h, const float* __restrict__ x,
    const int* __restrict__ ei, int E,
    const short* __restrict__ We1p, const float* __restrict__ We1,
    const float* __restrict__ be1,
    const short* __restrict__ We2p, const float* __restrict__ be2,
    const float* __restrict__ Wg, const float* __restrict__ bg,
    const short* __restrict__ Wc1p, const float* __restrict__ bc1,
    const float* __restrict__ Wc2, const float* __restrict__ bc2,
    float* __restrict__ m_aggr, float* __restrict__ coord_aggr)
{
    __shared__ short sStage[64 * 256];          // 32KB  [64 edges][256 k] bf16, XOR swizzle
    __shared__ float s_be1[128], s_w256[128], s_be2[128];
    __shared__ float s_wg[128], s_bc1[128], s_wc2[128];
    __shared__ int   s_col[64], s_row[64];

    const int tid  = threadIdx.x;
    const int lane = tid & 63;
    const int w    = tid >> 6;
    const int l15  = lane & 15;
    const int g    = lane >> 4;
    const int e0   = blockIdx.x * 64;

    if (tid < 64) {
        s_row[tid] = ei[e0 + tid];
        s_col[tid] = ei[E + e0 + tid];
    }
    if (tid < 128) {
        s_be1[tid]  = be1[tid];
        s_w256[tid] = We1[(size_t)256 * HID + tid];
        s_be2[tid]  = be2[tid];
        s_wg[tid]   = Wg[tid];
        s_bc1[tid]  = bc1[tid];
        s_wc2[tid]  = Wc2[tid];
    }
    __syncthreads();

    // ---- stage msg^T rows: each wave-iteration stages one full row (512B) coalesced
    #pragma unroll
    for (int it = 0; it < 16; ++it) {
        int e = w + 4 * it;
        int q = lane;
        int node = (q < 32) ? s_col[e] : s_row[e];
        float4 v = *(const float4*)&h[(size_t)node * HID + (size_t)(q & 31) * 4];
        uint2 pk;
        pk.x = cvt_pk(v.x, v.y);
        pk.y = cvt_pk(v.z, v.w);
        *(uint2*)((char*)sStage + e * 512 + ((q * 8) ^ ((e & 7) << 4))) = pk;
    }

    // ---- per-lane edge geometry (4x duplicated across g; cheap)
    const int eloc = w * 16 + l15;
    const int nr = s_row[eloc], nc = s_col[eloc];
    float dx = x[nc * 3 + 0] - x[nr * 3 + 0];
    float dy = x[nc * 3 + 1] - x[nr * 3 + 1];
    float dz = x[nc * 3 + 2] - x[nr * 3 + 2];
    float dist = sqrtf(dx * dx + dy * dy + dz * dz);
    __syncthreads();

    const char* stageRow = (const char*)sStage + eloc * 512;
    const int sw = (eloc & 7) << 4;
    const bf16x8* A1 = (const bf16x8*)We1p;
    const bf16x8* A2 = (const bf16x8*)We2p;
    const bf16x8* A3 = (const bf16x8*)Wc1p;

    // ---- L1: acc[mt] over features, K=256 (+ dist column folded into init)
    f32x4 acc[8];
    #pragma unroll
    for (int mt = 0; mt < 8; ++mt) {
        int f = mt * 16 + g * 4;
        #pragma unroll
        for (int r = 0; r < 4; ++r)
            acc[mt][r] = s_be1[f + r] + dist * s_w256[f + r];
    }
    #pragma unroll
    for (int kc = 0; kc < 8; ++kc) {
        int kb = kc * 64 + g * 8;
        uint2 lo = *(const uint2*)(stageRow + ((kb     ) ^ sw));
        uint2 hi = *(const uint2*)(stageRow + ((kb + 32) ^ sw));
        bf16x8 b; ((uint2*)&b)[0] = lo; ((uint2*)&b)[1] = hi;
        #pragma unroll
        for (int mt = 0; mt < 8; ++mt)
            acc[mt] = __builtin_amdgcn_mfma_f32_16x16x32_bf16(A1[(mt * 8 + kc) * 64 + lane], b, acc[mt], 0, 0, 0);
    }

    // ---- silu + pack B for L2 (pure register remap)
    bf16x8 Bn[4];
    #pragma unroll
    for (int kc = 0; kc < 4; ++kc) {
        unsigned* d = (unsigned*)&Bn[kc];
        d[0] = cvt_pk(silu_f(acc[2 * kc][0]),     silu_f(acc[2 * kc][1]));
        d[1] = cvt_pk(silu_f(acc[2 * kc][2]),     silu_f(acc[2 * kc][3]));
        d[2] = cvt_pk(silu_f(acc[2 * kc + 1][0]), silu_f(acc[2 * kc + 1][1]));
        d[3] = cvt_pk(silu_f(acc[2 * kc + 1][2]), silu_f(acc[2 * kc + 1][3]));
    }

    // ---- L2
    f32x4 acc2[8];
    #pragma unroll
    for (int mt = 0; mt < 8; ++mt) {
        int f = mt * 16 + g * 4;
        #pragma unroll
        for (int r = 0; r < 4; ++r) acc2[mt][r] = s_be2[f + r];
    }
    #pragma unroll
    for (int kc = 0; kc < 4; ++kc)
        #pragma unroll
        for (int mt = 0; mt < 8; ++mt)
            acc2[mt] = __builtin_amdgcn_mfma_f32_16x16x32_bf16(A2[(mt * 4 + kc) * 64 + lane], Bn[kc], acc2[mt], 0, 0, 0);

    // ---- silu + gate partial dot (per-lane covers its 32 features)
    float gp = 0.f;
    #pragma unroll
    for (int mt = 0; mt < 8; ++mt) {
        int f = mt * 16 + g * 4;
        #pragma unroll
        for (int r = 0; r < 4; ++r) {
            float sv = silu_f(acc2[mt][r]);
            acc2[mt][r] = sv;
            gp += sv * s_wg[f + r];
        }
    }
    gp += __shfl_xor(gp, 16, 64);
    gp += __shfl_xor(gp, 32, 64);
    float gate = sigmoid_f(gp + bg[0]);

    // ---- gate + m_aggr scatter
    float* pm = m_aggr + (size_t)nc * HID + g * 4;
    #pragma unroll
    for (int mt = 0; mt < 8; ++mt)
        #pragma unroll
        for (int r = 0; r < 4; ++r) {
            acc2[mt][r] *= gate;
            atomicAdd(pm + mt * 16 + r, acc2[mt][r]);
        }

    // ---- pack gated m as B for L3
    bf16x8 B3[4];
    #pragma unroll
    for (int kc = 0; kc < 4; ++kc) {
        unsigned* d = (unsigned*)&B3[kc];
        d[0] = cvt_pk(acc2[2 * kc][0],     acc2[2 * kc][1]);
        d[1] = cvt_pk(acc2[2 * kc][2],     acc2[2 * kc][3]);
        d[2] = cvt_pk(acc2[2 * kc + 1][0], acc2[2 * kc + 1][1]);
        d[3] = cvt_pk(acc2[2 * kc + 1][2], acc2[2 * kc + 1][3]);
    }

    // ---- L3
    f32x4 acc3[8];
    #pragma unroll
    for (int mt = 0; mt < 8; ++mt) {
        int f = mt * 16 + g * 4;
        #pragma unroll
        for (int r = 0; r < 4; ++r) acc3[mt][r] = s_bc1[f + r];
    }
    #pragma unroll
    for (int kc = 0; kc < 4; ++kc)
        #pragma unroll
        for (int mt = 0; mt < 8; ++mt)
            acc3[mt] = __builtin_amdgcn_mfma_f32_16x16x32_bf16(A3[(mt * 4 + kc) * 64 + lane], B3[kc], acc3[mt], 0, 0, 0);

    // ---- coord weight dot + scatter
    float cwp = 0.f;
    #pragma unroll
    for (int mt = 0; mt < 8; ++mt) {
        int f = mt * 16 + g * 4;
        #pragma unroll
        for (int r = 0; r < 4; ++r)
            cwp += silu_f(acc3[mt][r]) * s_wc2[f + r];
    }
    cwp += __shfl_xor(cwp, 16, 64);
    cwp += __shfl_xor(cwp, 32, 64);
    float cw = cwp + bc2[0];
    if (g == 0) {
        atomicAdd(&coord_aggr[nc * 3 + 0], dx * cw);
        atomicAdd(&coord_aggr[nc * 3 + 1], dy * cw);
        atomicAdd(&coord_aggr[nc * 3 + 2], dz * cw);
    }
}

// ---------------------------------------------------------------------------
// Node kernel: same transposed structure. 64 nodes/block.
//   h_out = h + silu([h|m_aggr] @ Wn1 + bn1) @ Wn2 + bn2 ; x_out = x + coord_aggr
// ---------------------------------------------------------------------------
__global__ __launch_bounds__(256) void egnn_node_mfma(
    const float* __restrict__ h, const float* __restrict__ x,
    const float* __restrict__ m_aggr, const float* __restrict__ coord_aggr,
    const short* __restrict__ Wn1p, const float* __restrict__ bn1,
    const short* __restrict__ Wn2p, const float* __restrict__ bn2,
    float* __restrict__ h_out, float* __restrict__ x_out, int N)
{
    __shared__ short sStage[64 * 256];
    __shared__ float s_bn1[128], s_bn2[128];

    const int tid  = threadIdx.x;
    const int lane = tid & 63;
    const int w    = tid >> 6;
    const int l15  = lane & 15;
    const int g    = lane >> 4;
    const int n0   = blockIdx.x * 64;

    if (tid < 128) { s_bn1[tid] = bn1[tid]; s_bn2[tid] = bn2[tid]; }

    if (tid < 192) {
        int gi = n0 * 3 + tid;
        if (gi < 3 * N) x_out[gi] = x[gi] + coord_aggr[gi];
    }

    #pragma unroll
    for (int it = 0; it < 16; ++it) {
        int e = w + 4 * it;
        int q = lane;
        int node = min(n0 + e, N - 1);
        const float* src = (q < 32) ? &h[(size_t)node * HID + (size_t)q * 4]
                                    : &m_aggr[(size_t)node * HID + (size_t)(q & 31) * 4];
        float4 v = *(const float4*)src;
        uint2 pk;
        pk.x = cvt_pk(v.x, v.y);
        pk.y = cvt_pk(v.z, v.w);
        *(uint2*)((char*)sStage + e * 512 + ((q * 8) ^ ((e & 7) << 4))) = pk;
    }
    __syncthreads();

    const int nloc = w * 16 + l15;
    const int node = n0 + nloc;
    const char* stageRow = (const char*)sStage + nloc * 512;
    const int sw = (nloc & 7) << 4;
    const bf16x8* A1 = (const bf16x8*)Wn1p;
    const bf16x8* A2 = (const bf16x8*)Wn2p;

    f32x4 acc[8];
    #pragma unroll
    for (int mt = 0; mt < 8; ++mt) {
        int f = mt * 16 + g * 4;
        #pragma unroll
        for (int r = 0; r < 4; ++r) acc[mt][r] = s_bn1[f + r];
    }
    #pragma unroll
    for (int kc = 0; kc < 8; ++kc) {
        int kb = kc * 64 + g * 8;
        uint2 lo = *(const uint2*)(stageRow + ((kb     ) ^ sw));
        uint2 hi = *(const uint2*)(stageRow + ((kb + 32) ^ sw));
        bf16x8 b; ((uint2*)&b)[0] = lo; ((uint2*)&b)[1] = hi;
        #pragma unroll
        for (int mt = 0; mt < 8; ++mt)
            acc[mt] = __builtin_amdgcn_mfma_f32_16x16x32_bf16(A1[(mt * 8 + kc) * 64 + lane], b, acc[mt], 0, 0, 0);
    }

    bf16x8 Bn[4];
    #pragma unroll
    for (int kc = 0; kc < 4; ++kc) {
        unsigned* d = (unsigned*)&Bn[kc];
        d[0] = cvt_pk(silu_f(acc[2 * kc][0]),     silu_f(acc[2 * kc][1]));
        d[1] = cvt_pk(silu_f(acc[2 * kc][2]),     silu_f(acc[2 * kc][3]));
        d[2] = cvt_pk(silu_f(acc[2 * kc + 1][0]), silu_f(acc[2 * kc + 1][1]));
        d[3] = cvt_pk(silu_f(acc[2 * kc + 1][2]), silu_f(acc[2 * kc + 1][3]));
    }

    f32x4 acc2[8];
    #pragma unroll
    for (int mt = 0; mt < 8; ++mt) {
        int f = mt * 16 + g * 4;
        #pragma unroll
        for (int r = 0; r < 4; ++r) acc2[mt][r] = s_bn2[f + r];
    }
    #pragma unroll
    for (int kc = 0; kc < 4; ++kc)
        #pragma unroll
        for (int mt = 0; mt < 8; ++mt)
            acc2[mt] = __builtin_amdgcn_mfma_f32_16x16x32_bf16(A2[(mt * 4 + kc) * 64 + lane], Bn[kc], acc2[mt], 0, 0, 0);

    if (node < N) {
        #pragma unroll
        for (int mt = 0; mt < 8; ++mt) {
            size_t base = (size_t)node * HID + mt * 16 + g * 4;
            float4 hres = *(const float4*)&h[base];
            float4 o;
            o.x = acc2[mt][0] + hres.x;
            o.y = acc2[mt][1] + hres.y;
            o.z = acc2[mt][2] + hres.z;
            o.w = acc2[mt][3] + hres.w;
            *(float4*)&h_out[base] = o;
        }
    }
}

extern "C" void kernel_launch(void* const* d_in, const int* in_sizes, int n_in,
                              void* d_out, int out_size, void* d_ws, size_t ws_size,
                              hipStream_t stream) {
    const float* h   = (const float*)d_in[0];
    const float* x   = (const float*)d_in[1];
    const int*   ei  = (const int*)d_in[2];
    const float* We1 = (const float*)d_in[3];
    const float* be1 = (const float*)d_in[4];
    const float* We2 = (const float*)d_in[5];
    const float* be2 = (const float*)d_in[6];
    const float* Wg  = (const float*)d_in[7];
    const float* bg  = (const float*)d_in[8];
    const float* Wn1 = (const float*)d_in[9];
    const float* bn1 = (const float*)d_in[10];
    const float* Wn2 = (const float*)d_in[11];
    const float* bn2 = (const float*)d_in[12];
    const float* Wc1 = (const float*)d_in[13];
    const float* bc1 = (const float*)d_in[14];
    const float* Wc2 = (const float*)d_in[15];
    const float* bc2 = (const float*)d_in[16];

    const int N = in_sizes[0] / HID;
    const int E = in_sizes[2] / 2;

    float* m_aggr     = (float*)d_ws;
    float* coord_aggr = m_aggr + (size_t)N * HID;
    short* We1p       = (short*)(coord_aggr + (size_t)N * 3);  // 256*128
    short* We2p       = We1p + 256 * 128;                      // 128*128
    short* Wc1p       = We2p + 128 * 128;                      // 128*128
    short* Wn1p       = Wc1p + 128 * 128;                      // 256*128
    short* Wn2p       = Wn1p + 256 * 128;                      // 128*128

    hipMemsetAsync(d_ws, 0, (size_t)N * (HID + 3) * sizeof(float), stream);

    float* h_out = (float*)d_out;
    float* x_out = h_out + (size_t)N * HID;

    egnn_prep<<<dim3(56), dim3(256), 0, stream>>>(
        We1, We2, Wc1, Wn1, Wn2, We1p, We2p, Wc1p, Wn1p, Wn2p);
    egnn_edge_mfma<<<dim3((E + 63) / 64), dim3(256), 0, stream>>>(
        h, x, ei, E, We1p, We1, be1, We2p, be2, Wg, bg, Wc1p, bc1, Wc2, bc2,
        m_aggr, coord_aggr);
    egnn_node_mfma<<<dim3((N + 63) / 64), dim3(256), 0, stream>>>(
        h, x, m_aggr, coord_aggr, Wn1p, bn1, Wn2p, bn2, h_out, x_out, N);
}

// Round 4
// 480.286 us; speedup vs baseline: 2.5080x; 2.5080x over previous
//
#include <hip/hip_runtime.h>
#include <cmath>

#define HID 128

typedef __attribute__((ext_vector_type(8))) short bf16x8;
typedef __attribute__((ext_vector_type(4))) float f32x4;

__device__ __forceinline__ unsigned short f2bf(float f) {
    union { float f; unsigned int i; } c; c.f = f;
    unsigned int r = c.i + 0x7fffu + ((c.i >> 16) & 1u);
    return (unsigned short)(r >> 16);
}
__device__ __forceinline__ unsigned cvt_pk(float lo, float hi) {
    unsigned r;
    asm("v_cvt_pk_bf16_f32 %0, %1, %2" : "=v"(r) : "v"(lo), "v"(hi));
    return r;
}
__device__ __forceinline__ float silu_f(float v) {
    float t = __builtin_amdgcn_exp2f(-1.44269504f * v);
    return v * __builtin_amdgcn_rcpf(1.0f + t);
}
__device__ __forceinline__ float sigmoid_f(float v) {
    return __builtin_amdgcn_rcpf(1.0f + __builtin_amdgcn_exp2f(-1.44269504f * v));
}

// ---------------------------------------------------------------------------
// Weight prep: A-fragments of W^T. For output-feature tile nt, k-chunk kc:
//   dst[((nt*KC + kc)*64 + lane)*8 + j] = W[k][nt*16 + (lane&15)]
//   k = kc*32 + (lane>>4)*4 + (j&3) + 16*(j>>2)
// ---------------------------------------------------------------------------
__global__ __launch_bounds__(256) void egnn_prep(
    const float* __restrict__ We1, const float* __restrict__ We2,
    const float* __restrict__ Wc1, const float* __restrict__ Wn1,
    const float* __restrict__ Wn2,
    short* __restrict__ We1p, short* __restrict__ We2p, short* __restrict__ Wc1p,
    short* __restrict__ Wn1p, short* __restrict__ Wn2p)
{
    int t = blockIdx.x * 256 + threadIdx.x;
    int frag = t >> 6, lane = t & 63;
    if (frag >= 224) return;
    const float* W; short* dst; int KC, f;
    if (frag < 64)       { W = We1; dst = We1p; KC = 8; f = frag; }
    else if (frag < 96)  { W = We2; dst = We2p; KC = 4; f = frag - 64; }
    else if (frag < 128) { W = Wc1; dst = Wc1p; KC = 4; f = frag - 96; }
    else if (frag < 192) { W = Wn1; dst = Wn1p; KC = 8; f = frag - 128; }
    else                 { W = Wn2; dst = Wn2p; KC = 4; f = frag - 192; }
    int nt = f / KC, kc = f % KC;
    int n = nt * 16 + (lane & 15);
    short* d = dst + (((size_t)nt * KC + kc) * 64 + lane) * 8;
    #pragma unroll
    for (int j = 0; j < 8; ++j) {
        int k = kc * 32 + ((lane >> 4) << 2) + (j & 3) + ((j >> 2) << 4);
        d[j] = (short)f2bf(W[(size_t)k * HID + n]);
    }
}

// ---------------------------------------------------------------------------
// Edge kernel: 64 edges/block, 4 waves; wave w owns edges w*16..w*16+15.
// Layers chain in-register; m_aggr scatter goes through wave-private LDS
// rows to restore dense (8 lines/edge) atomic coalescing.
// ---------------------------------------------------------------------------
__global__ __launch_bounds__(256) void egnn_edge_mfma(
    const float* __restrict__ h, const float* __restrict__ x,
    const int* __restrict__ ei, int E,
    const short* __restrict__ We1p, const float* __restrict__ We1,
    const float* __restrict__ be1,
    const short* __restrict__ We2p, const float* __restrict__ be2,
    const float* __restrict__ Wg, const float* __restrict__ bg,
    const short* __restrict__ Wc1p, const float* __restrict__ bc1,
    const float* __restrict__ Wc2, const float* __restrict__ bc2,
    float* __restrict__ m_aggr, float* __restrict__ coord_aggr)
{
    __shared__ short sStage[64 * 256];          // 32KB; reused as [64][128] f32 for scatter
    __shared__ float s_be1[128], s_w256[128], s_be2[128];
    __shared__ float s_wg[128], s_bc1[128], s_wc2[128];
    __shared__ int   s_col[64], s_row[64];

    const int tid  = threadIdx.x;
    const int lane = tid & 63;
    const int w    = tid >> 6;
    const int l15  = lane & 15;
    const int g    = lane >> 4;
    const int e0   = blockIdx.x * 64;

    if (tid < 64) {
        s_row[tid] = ei[e0 + tid];
        s_col[tid] = ei[E + e0 + tid];
    }
    if (tid < 128) {
        s_be1[tid]  = be1[tid];
        s_w256[tid] = We1[(size_t)256 * HID + tid];
        s_be2[tid]  = be2[tid];
        s_wg[tid]   = Wg[tid];
        s_bc1[tid]  = bc1[tid];
        s_wc2[tid]  = Wc2[tid];
    }
    __syncthreads();

    // ---- stage msg^T rows (bf16, XOR swizzle), one 512B row per wave-iter
    #pragma unroll
    for (int it = 0; it < 16; ++it) {
        int e = w + 4 * it;
        int q = lane;
        int node = (q < 32) ? s_col[e] : s_row[e];
        float4 v = *(const float4*)&h[(size_t)node * HID + (size_t)(q & 31) * 4];
        uint2 pk;
        pk.x = cvt_pk(v.x, v.y);
        pk.y = cvt_pk(v.z, v.w);
        *(uint2*)((char*)sStage + e * 512 + ((q * 8) ^ ((e & 7) << 4))) = pk;
    }

    // ---- per-lane edge geometry
    const int eloc = w * 16 + l15;
    const int nr = s_row[eloc], nc = s_col[eloc];
    float dx = x[nc * 3 + 0] - x[nr * 3 + 0];
    float dy = x[nc * 3 + 1] - x[nr * 3 + 1];
    float dz = x[nc * 3 + 2] - x[nr * 3 + 2];
    float dist = sqrtf(dx * dx + dy * dy + dz * dz);
    __syncthreads();

    const char* stageRow = (const char*)sStage + eloc * 512;
    const int sw = (eloc & 7) << 4;
    const bf16x8* A1 = (const bf16x8*)We1p;
    const bf16x8* A2 = (const bf16x8*)We2p;
    const bf16x8* A3 = (const bf16x8*)Wc1p;

    // ---- L1: K=256 (+ dist column folded into init)
    f32x4 acc[8];
    #pragma unroll
    for (int mt = 0; mt < 8; ++mt) {
        int f = mt * 16 + g * 4;
        #pragma unroll
        for (int r = 0; r < 4; ++r)
            acc[mt][r] = s_be1[f + r] + dist * s_w256[f + r];
    }
    #pragma unroll
    for (int kc = 0; kc < 8; ++kc) {
        int kb = kc * 64 + g * 8;
        uint2 lo = *(const uint2*)(stageRow + ((kb     ) ^ sw));
        uint2 hi = *(const uint2*)(stageRow + ((kb + 32) ^ sw));
        bf16x8 b; ((uint2*)&b)[0] = lo; ((uint2*)&b)[1] = hi;
        #pragma unroll
        for (int mt = 0; mt < 8; ++mt)
            acc[mt] = __builtin_amdgcn_mfma_f32_16x16x32_bf16(A1[(mt * 8 + kc) * 64 + lane], b, acc[mt], 0, 0, 0);
    }

    // ---- silu + pack B for L2 (register remap only)
    bf16x8 Bn[4];
    #pragma unroll
    for (int kc = 0; kc < 4; ++kc) {
        unsigned* d = (unsigned*)&Bn[kc];
        d[0] = cvt_pk(silu_f(acc[2 * kc][0]),     silu_f(acc[2 * kc][1]));
        d[1] = cvt_pk(silu_f(acc[2 * kc][2]),     silu_f(acc[2 * kc][3]));
        d[2] = cvt_pk(silu_f(acc[2 * kc + 1][0]), silu_f(acc[2 * kc + 1][1]));
        d[3] = cvt_pk(silu_f(acc[2 * kc + 1][2]), silu_f(acc[2 * kc + 1][3]));
    }

    // ---- L2
    f32x4 acc2[8];
    #pragma unroll
    for (int mt = 0; mt < 8; ++mt) {
        int f = mt * 16 + g * 4;
        #pragma unroll
        for (int r = 0; r < 4; ++r) acc2[mt][r] = s_be2[f + r];
    }
    #pragma unroll
    for (int kc = 0; kc < 4; ++kc)
        #pragma unroll
        for (int mt = 0; mt < 8; ++mt)
            acc2[mt] = __builtin_amdgcn_mfma_f32_16x16x32_bf16(A2[(mt * 4 + kc) * 64 + lane], Bn[kc], acc2[mt], 0, 0, 0);

    // ---- silu + gate partial dot
    float gp = 0.f;
    #pragma unroll
    for (int mt = 0; mt < 8; ++mt) {
        int f = mt * 16 + g * 4;
        #pragma unroll
        for (int r = 0; r < 4; ++r) {
            float sv = silu_f(acc2[mt][r]);
            acc2[mt][r] = sv;
            gp += sv * s_wg[f + r];
        }
    }
    gp += __shfl_xor(gp, 16, 64);
    gp += __shfl_xor(gp, 32, 64);
    float gate = sigmoid_f(gp + bg[0]);

    // ---- apply gate; write gated m (f32) to wave-private LDS row.
    // sStage rows [w*16, w*16+16) were only ever read by this wave (L1 done),
    // and other waves never touch them -> no barrier needed.
    #pragma unroll
    for (int mt = 0; mt < 8; ++mt) {
        f32x4 v;
        #pragma unroll
        for (int r = 0; r < 4; ++r) { acc2[mt][r] *= gate; v[r] = acc2[mt][r]; }
        *(f32x4*)((char*)sStage + eloc * 512 + ((g * 16 + mt * 64) ^ sw)) = v;
    }

    // ---- pack gated m as B for L3 (from registers)
    bf16x8 B3[4];
    #pragma unroll
    for (int kc = 0; kc < 4; ++kc) {
        unsigned* d = (unsigned*)&B3[kc];
        d[0] = cvt_pk(acc2[2 * kc][0],     acc2[2 * kc][1]);
        d[1] = cvt_pk(acc2[2 * kc][2],     acc2[2 * kc][3]);
        d[2] = cvt_pk(acc2[2 * kc + 1][0], acc2[2 * kc + 1][1]);
        d[3] = cvt_pk(acc2[2 * kc + 1][2], acc2[2 * kc + 1][3]);
    }

    // ---- dense m_aggr scatter: wave iterates its 16 edges, 64 lanes cover
    // 128 consecutive floats in 2 atomics -> 8 fully-covered 64B lines/edge.
    // Issued before L3 MFMAs so the RMWs drain under compute.
    #pragma unroll
    for (int i = 0; i < 16; ++i) {
        int e = w * 16 + i;
        int c = s_col[e];
        int swE = (e & 7) << 4;
        float v0 = *(const float*)((const char*)sStage + e * 512 + (((lane * 4)      ) ^ swE));
        float v1 = *(const float*)((const char*)sStage + e * 512 + (((lane * 4) + 256) ^ swE));
        float* dst = m_aggr + (size_t)c * HID + lane;
        atomicAdd(dst, v0);
        atomicAdd(dst + 64, v1);
    }

    // ---- L3
    f32x4 acc3[8];
    #pragma unroll
    for (int mt = 0; mt < 8; ++mt) {
        int f = mt * 16 + g * 4;
        #pragma unroll
        for (int r = 0; r < 4; ++r) acc3[mt][r] = s_bc1[f + r];
    }
    #pragma unroll
    for (int kc = 0; kc < 4; ++kc)
        #pragma unroll
        for (int mt = 0; mt < 8; ++mt)
            acc3[mt] = __builtin_amdgcn_mfma_f32_16x16x32_bf16(A3[(mt * 4 + kc) * 64 + lane], B3[kc], acc3[mt], 0, 0, 0);

    // ---- coord weight dot + scatter
    float cwp = 0.f;
    #pragma unroll
    for (int mt = 0; mt < 8; ++mt) {
        int f = mt * 16 + g * 4;
        #pragma unroll
        for (int r = 0; r < 4; ++r)
            cwp += silu_f(acc3[mt][r]) * s_wc2[f + r];
    }
    cwp += __shfl_xor(cwp, 16, 64);
    cwp += __shfl_xor(cwp, 32, 64);
    float cw = cwp + bc2[0];
    if (g == 0) {
        atomicAdd(&coord_aggr[nc * 3 + 0], dx * cw);
        atomicAdd(&coord_aggr[nc * 3 + 1], dy * cw);
        atomicAdd(&coord_aggr[nc * 3 + 2], dz * cw);
    }
}

// ---------------------------------------------------------------------------
// Node kernel: transposed structure, 64 nodes/block.
// ---------------------------------------------------------------------------
__global__ __launch_bounds__(256) void egnn_node_mfma(
    const float* __restrict__ h, const float* __restrict__ x,
    const float* __restrict__ m_aggr, const float* __restrict__ coord_aggr,
    const short* __restrict__ Wn1p, const float* __restrict__ bn1,
    const short* __restrict__ Wn2p, const float* __restrict__ bn2,
    float* __restrict__ h_out, float* __restrict__ x_out, int N)
{
    __shared__ short sStage[64 * 256];
    __shared__ float s_bn1[128], s_bn2[128];

    const int tid  = threadIdx.x;
    const int lane = tid & 63;
    const int w    = tid >> 6;
    const int l15  = lane & 15;
    const int g    = lane >> 4;
    const int n0   = blockIdx.x * 64;

    if (tid < 128) { s_bn1[tid] = bn1[tid]; s_bn2[tid] = bn2[tid]; }

    if (tid < 192) {
        int gi = n0 * 3 + tid;
        if (gi < 3 * N) x_out[gi] = x[gi] + coord_aggr[gi];
    }

    #pragma unroll
    for (int it = 0; it < 16; ++it) {
        int e = w + 4 * it;
        int q = lane;
        int node = min(n0 + e, N - 1);
        const float* src = (q < 32) ? &h[(size_t)node * HID + (size_t)q * 4]
                                    : &m_aggr[(size_t)node * HID + (size_t)(q & 31) * 4];
        float4 v = *(const float4*)src;
        uint2 pk;
        pk.x = cvt_pk(v.x, v.y);
        pk.y = cvt_pk(v.z, v.w);
        *(uint2*)((char*)sStage + e * 512 + ((q * 8) ^ ((e & 7) << 4))) = pk;
    }
    __syncthreads();

    const int nloc = w * 16 + l15;
    const int node = n0 + nloc;
    const char* stageRow = (const char*)sStage + nloc * 512;
    const int sw = (nloc & 7) << 4;
    const bf16x8* A1 = (const bf16x8*)Wn1p;
    const bf16x8* A2 = (const bf16x8*)Wn2p;

    f32x4 acc[8];
    #pragma unroll
    for (int mt = 0; mt < 8; ++mt) {
        int f = mt * 16 + g * 4;
        #pragma unroll
        for (int r = 0; r < 4; ++r) acc[mt][r] = s_bn1[f + r];
    }
    #pragma unroll
    for (int kc = 0; kc < 8; ++kc) {
        int kb = kc * 64 + g * 8;
        uint2 lo = *(const uint2*)(stageRow + ((kb     ) ^ sw));
        uint2 hi = *(const uint2*)(stageRow + ((kb + 32) ^ sw));
        bf16x8 b; ((uint2*)&b)[0] = lo; ((uint2*)&b)[1] = hi;
        #pragma unroll
        for (int mt = 0; mt < 8; ++mt)
            acc[mt] = __builtin_amdgcn_mfma_f32_16x16x32_bf16(A1[(mt * 8 + kc) * 64 + lane], b, acc[mt], 0, 0, 0);
    }

    bf16x8 Bn[4];
    #pragma unroll
    for (int kc = 0; kc < 4; ++kc) {
        unsigned* d = (unsigned*)&Bn[kc];
        d[0] = cvt_pk(silu_f(acc[2 * kc][0]),     silu_f(acc[2 * kc][1]));
        d[1] = cvt_pk(silu_f(acc[2 * kc][2]),     silu_f(acc[2 * kc][3]));
        d[2] = cvt_pk(silu_f(acc[2 * kc + 1][0]), silu_f(acc[2 * kc + 1][1]));
        d[3] = cvt_pk(silu_f(acc[2 * kc + 1][2]), silu_f(acc[2 * kc + 1][3]));
    }

    f32x4 acc2[8];
    #pragma unroll
    for (int mt = 0; mt < 8; ++mt) {
        int f = mt * 16 + g * 4;
        #pragma unroll
        for (int r = 0; r < 4; ++r) acc2[mt][r] = s_bn2[f + r];
    }
    #pragma unroll
    for (int kc = 0; kc < 4; ++kc)
        #pragma unroll
        for (int mt = 0; mt < 8; ++mt)
            acc2[mt] = __builtin_amdgcn_mfma_f32_16x16x32_bf16(A2[(mt * 4 + kc) * 64 + lane], Bn[kc], acc2[mt], 0, 0, 0);

    if (node < N) {
        #pragma unroll
        for (int mt = 0; mt < 8; ++mt) {
            size_t base = (size_t)node * HID + mt * 16 + g * 4;
            float4 hres = *(const float4*)&h[base];
            float4 o;
            o.x = acc2[mt][0] + hres.x;
            o.y = acc2[mt][1] + hres.y;
            o.z = acc2[mt][2] + hres.z;
            o.w = acc2[mt][3] + hres.w;
            *(float4*)&h_out[base] = o;
        }
    }
}

extern "C" void kernel_launch(void* const* d_in, const int* in_sizes, int n_in,
                              void* d_out, int out_size, void* d_ws, size_t ws_size,
                              hipStream_t stream) {
    const float* h   = (const float*)d_in[0];
    const float* x   = (const float*)d_in[1];
    const int*   ei  = (const int*)d_in[2];
    const float* We1 = (const float*)d_in[3];
    const float* be1 = (const float*)d_in[4];
    const float* We2 = (const float*)d_in[5];
    const float* be2 = (const float*)d_in[6];
    const float* Wg  = (const float*)d_in[7];
    const float* bg  = (const float*)d_in[8];
    const float* Wn1 = (const float*)d_in[9];
    const float* bn1 = (const float*)d_in[10];
    const float* Wn2 = (const float*)d_in[11];
    const float* bn2 = (const float*)d_in[12];
    const float* Wc1 = (const float*)d_in[13];
    const float* bc1 = (const float*)d_in[14];
    const float* Wc2 = (const float*)d_in[15];
    const float* bc2 = (const float*)d_in[16];

    const int N = in_sizes[0] / HID;
    const int E = in_sizes[2] / 2;

    float* m_aggr     = (float*)d_ws;
    float* coord_aggr = m_aggr + (size_t)N * HID;
    short* We1p       = (short*)(coord_aggr + (size_t)N * 3);  // 256*128
    short* We2p       = We1p + 256 * 128;                      // 128*128
    short* Wc1p       = We2p + 128 * 128;                      // 128*128
    short* Wn1p       = Wc1p + 128 * 128;                      // 256*128
    short* Wn2p       = Wn1p + 256 * 128;                      // 128*128

    hipMemsetAsync(d_ws, 0, (size_t)N * (HID + 3) * sizeof(float), stream);

    float* h_out = (float*)d_out;
    float* x_out = h_out + (size_t)N * HID;

    egnn_prep<<<dim3(56), dim3(256), 0, stream>>>(
        We1, We2, Wc1, Wn1, Wn2, We1p, We2p, Wc1p, Wn1p, Wn2p);
    egnn_edge_mfma<<<dim3((E + 63) / 64), dim3(256), 0, stream>>>(
        h, x, ei, E, We1p, We1, be1, We2p, be2, Wg, bg, Wc1p, bc1, Wc2, bc2,
        m_aggr, coord_aggr);
    egnn_node_mfma<<<dim3((N + 63) / 64), dim3(256), 0, stream>>>(
        h, x, m_aggr, coord_aggr, Wn1p, bn1, Wn2p, bn2, h_out, x_out, N);
}

// Round 6
// 377.986 us; speedup vs baseline: 3.1868x; 1.2706x over previous
//
#include <hip/hip_runtime.h>
#include <cmath>

#define HID 128

typedef __attribute__((ext_vector_type(8))) short bf16x8;
typedef __attribute__((ext_vector_type(4))) float f32x4;

__device__ __forceinline__ unsigned short f2bf(float f) {
    union { float f; unsigned int i; } c; c.f = f;
    unsigned int r = c.i + 0x7fffu + ((c.i >> 16) & 1u);
    return (unsigned short)(r >> 16);
}
__device__ __forceinline__ unsigned cvt_pk(float lo, float hi) {
    unsigned r;
    asm("v_cvt_pk_bf16_f32 %0, %1, %2" : "=v"(r) : "v"(lo), "v"(hi));
    return r;
}
__device__ __forceinline__ float silu_f(float v) {
    float t = __builtin_amdgcn_exp2f(-1.44269504f * v);
    return v * __builtin_amdgcn_rcpf(1.0f + t);
}
__device__ __forceinline__ float sigmoid_f(float v) {
    return __builtin_amdgcn_rcpf(1.0f + __builtin_amdgcn_exp2f(-1.44269504f * v));
}
// packed 2xf16 global atomic add (gfx942/gfx950)
typedef __fp16 fp16x2 __attribute__((ext_vector_type(2)));
__device__ __forceinline__ void atomic_pk_add_f16(void* p, float lo, float hi) {
    union { fp16x2 h; unsigned u; } cv;
    cv.h = __builtin_amdgcn_cvt_pkrtz(lo, hi);
    unsigned long long a = (unsigned long long)p;
    asm volatile("global_atomic_pk_add_f16 %0, %1, off" :: "v"(a), "v"(cv.u) : "memory");
}

// ---------------------------------------------------------------------------
// Weight prep: A-fragments of W^T. For output-feature tile nt, k-chunk kc:
//   dst[((nt*KC + kc)*64 + lane)*8 + j] = W[k][nt*16 + (lane&15)]
//   k = kc*32 + (lane>>4)*4 + (j&3) + 16*(j>>2)
// ---------------------------------------------------------------------------
__global__ __launch_bounds__(256) void egnn_prep(
    const float* __restrict__ We1, const float* __restrict__ We2,
    const float* __restrict__ Wc1, const float* __restrict__ Wn1,
    const float* __restrict__ Wn2,
    short* __restrict__ We1p, short* __restrict__ We2p, short* __restrict__ Wc1p,
    short* __restrict__ Wn1p, short* __restrict__ Wn2p)
{
    int t = blockIdx.x * 256 + threadIdx.x;
    int frag = t >> 6, lane = t & 63;
    if (frag >= 224) return;
    const float* W; short* dst; int KC, f;
    if (frag < 64)       { W = We1; dst = We1p; KC = 8; f = frag; }
    else if (frag < 96)  { W = We2; dst = We2p; KC = 4; f = frag - 64; }
    else if (frag < 128) { W = Wc1; dst = Wc1p; KC = 4; f = frag - 96; }
    else if (frag < 192) { W = Wn1; dst = Wn1p; KC = 8; f = frag - 128; }
    else                 { W = Wn2; dst = Wn2p; KC = 4; f = frag - 192; }
    int nt = f / KC, kc = f % KC;
    int n = nt * 16 + (lane & 15);
    short* d = dst + (((size_t)nt * KC + kc) * 64 + lane) * 8;
    #pragma unroll
    for (int j = 0; j < 8; ++j) {
        int k = kc * 32 + ((lane >> 4) << 2) + (j & 3) + ((j >> 2) << 4);
        d[j] = (short)f2bf(W[(size_t)k * HID + n]);
    }
}

// ---------------------------------------------------------------------------
// Edge kernel: 64 edges/block, 4 waves; wave w owns edges w*16..w*16+15.
// Layers chain in-register; m scatter = packed-f16 atomics through a
// wave-private LDS row (1 atomic instr covers a full 256B f16 row/edge).
// ---------------------------------------------------------------------------
__global__ __launch_bounds__(256) void egnn_edge_mfma(
    const float* __restrict__ h, const float* __restrict__ x,
    const int* __restrict__ ei, int E,
    const short* __restrict__ We1p, const float* __restrict__ We1,
    const float* __restrict__ be1,
    const short* __restrict__ We2p, const float* __restrict__ be2,
    const float* __restrict__ Wg, const float* __restrict__ bg,
    const short* __restrict__ Wc1p, const float* __restrict__ bc1,
    const float* __restrict__ Wc2, const float* __restrict__ bc2,
    short* __restrict__ m16, float* __restrict__ coord_aggr)
{
    __shared__ short sStage[64 * 256];          // 32KB; reused as [64][128] f32 for scatter
    __shared__ float s_be1[128], s_w256[128], s_be2[128];
    __shared__ float s_wg[128], s_bc1[128], s_wc2[128];
    __shared__ int   s_col[64], s_row[64];

    const int tid  = threadIdx.x;
    const int lane = tid & 63;
    const int w    = tid >> 6;
    const int l15  = lane & 15;
    const int g    = lane >> 4;
    const int e0   = blockIdx.x * 64;

    if (tid < 64) {
        s_row[tid] = ei[e0 + tid];
        s_col[tid] = ei[E + e0 + tid];
    }
    if (tid < 128) {
        s_be1[tid]  = be1[tid];
        s_w256[tid] = We1[(size_t)256 * HID + tid];
        s_be2[tid]  = be2[tid];
        s_wg[tid]   = Wg[tid];
        s_bc1[tid]  = bc1[tid];
        s_wc2[tid]  = Wc2[tid];
    }
    __syncthreads();

    // ---- stage msg^T rows (bf16, XOR swizzle), one 512B row per wave-iter
    #pragma unroll
    for (int it = 0; it < 16; ++it) {
        int e = w + 4 * it;
        int q = lane;
        int node = (q < 32) ? s_col[e] : s_row[e];
        float4 v = *(const float4*)&h[(size_t)node * HID + (size_t)(q & 31) * 4];
        uint2 pk;
        pk.x = cvt_pk(v.x, v.y);
        pk.y = cvt_pk(v.z, v.w);
        *(uint2*)((char*)sStage + e * 512 + ((q * 8) ^ ((e & 7) << 4))) = pk;
    }

    // ---- per-lane edge geometry
    const int eloc = w * 16 + l15;
    const int nr = s_row[eloc], nc = s_col[eloc];
    float dx = x[nc * 3 + 0] - x[nr * 3 + 0];
    float dy = x[nc * 3 + 1] - x[nr * 3 + 1];
    float dz = x[nc * 3 + 2] - x[nr * 3 + 2];
    float dist = sqrtf(dx * dx + dy * dy + dz * dz);
    __syncthreads();

    const char* stageRow = (const char*)sStage + eloc * 512;
    const int sw = (eloc & 7) << 4;
    const bf16x8* A1 = (const bf16x8*)We1p;
    const bf16x8* A2 = (const bf16x8*)We2p;
    const bf16x8* A3 = (const bf16x8*)Wc1p;

    // ---- L1: K=256 (+ dist column folded into init)
    f32x4 acc[8];
    #pragma unroll
    for (int mt = 0; mt < 8; ++mt) {
        int f = mt * 16 + g * 4;
        #pragma unroll
        for (int r = 0; r < 4; ++r)
            acc[mt][r] = s_be1[f + r] + dist * s_w256[f + r];
    }
    #pragma unroll
    for (int kc = 0; kc < 8; ++kc) {
        int kb = kc * 64 + g * 8;
        uint2 lo = *(const uint2*)(stageRow + ((kb     ) ^ sw));
        uint2 hi = *(const uint2*)(stageRow + ((kb + 32) ^ sw));
        bf16x8 b; ((uint2*)&b)[0] = lo; ((uint2*)&b)[1] = hi;
        #pragma unroll
        for (int mt = 0; mt < 8; ++mt)
            acc[mt] = __builtin_amdgcn_mfma_f32_16x16x32_bf16(A1[(mt * 8 + kc) * 64 + lane], b, acc[mt], 0, 0, 0);
    }

    // ---- silu + pack B for L2 (register remap only)
    bf16x8 Bn[4];
    #pragma unroll
    for (int kc = 0; kc < 4; ++kc) {
        unsigned* d = (unsigned*)&Bn[kc];
        d[0] = cvt_pk(silu_f(acc[2 * kc][0]),     silu_f(acc[2 * kc][1]));
        d[1] = cvt_pk(silu_f(acc[2 * kc][2]),     silu_f(acc[2 * kc][3]));
        d[2] = cvt_pk(silu_f(acc[2 * kc + 1][0]), silu_f(acc[2 * kc + 1][1]));
        d[3] = cvt_pk(silu_f(acc[2 * kc + 1][2]), silu_f(acc[2 * kc + 1][3]));
    }

    // ---- L2
    f32x4 acc2[8];
    #pragma unroll
    for (int mt = 0; mt < 8; ++mt) {
        int f = mt * 16 + g * 4;
        #pragma unroll
        for (int r = 0; r < 4; ++r) acc2[mt][r] = s_be2[f + r];
    }
    #pragma unroll
    for (int kc = 0; kc < 4; ++kc)
        #pragma unroll
        for (int mt = 0; mt < 8; ++mt)
            acc2[mt] = __builtin_amdgcn_mfma_f32_16x16x32_bf16(A2[(mt * 4 + kc) * 64 + lane], Bn[kc], acc2[mt], 0, 0, 0);

    // ---- silu + gate partial dot
    float gp = 0.f;
    #pragma unroll
    for (int mt = 0; mt < 8; ++mt) {
        int f = mt * 16 + g * 4;
        #pragma unroll
        for (int r = 0; r < 4; ++r) {
            float sv = silu_f(acc2[mt][r]);
            acc2[mt][r] = sv;
            gp += sv * s_wg[f + r];
        }
    }
    gp += __shfl_xor(gp, 16, 64);
    gp += __shfl_xor(gp, 32, 64);
    float gate = sigmoid_f(gp + bg[0]);

    // ---- apply gate; write gated m (f32) to wave-private LDS row.
    #pragma unroll
    for (int mt = 0; mt < 8; ++mt) {
        f32x4 v;
        #pragma unroll
        for (int r = 0; r < 4; ++r) { acc2[mt][r] *= gate; v[r] = acc2[mt][r]; }
        *(f32x4*)((char*)sStage + eloc * 512 + ((g * 16 + mt * 64) ^ sw)) = v;
    }

    // ---- pack gated m as B for L3 (from registers)
    bf16x8 B3[4];
    #pragma unroll
    for (int kc = 0; kc < 4; ++kc) {
        unsigned* d = (unsigned*)&B3[kc];
        d[0] = cvt_pk(acc2[2 * kc][0],     acc2[2 * kc][1]);
        d[1] = cvt_pk(acc2[2 * kc][2],     acc2[2 * kc][3]);
        d[2] = cvt_pk(acc2[2 * kc + 1][0], acc2[2 * kc + 1][1]);
        d[3] = cvt_pk(acc2[2 * kc + 1][2], acc2[2 * kc + 1][3]);
    }

    // ---- dense m scatter: per edge, 64 lanes cover all 128 features with
    // ONE packed-f16 atomic instr (features 2*lane, 2*lane+1) -> 4 full
    // 64B lines/edge, 64 ops/edge (vs 128 f32 ops). Issued before L3 MFMAs.
    #pragma unroll
    for (int i = 0; i < 16; ++i) {
        int e = w * 16 + i;
        int c = s_col[e];
        int swE = (e & 7) << 4;
        float2 v = *(const float2*)((const char*)sStage + e * 512 + ((lane * 8) ^ swE));
        atomic_pk_add_f16(m16 + (size_t)c * HID + lane * 2, v.x, v.y);
    }

    // ---- L3
    f32x4 acc3[8];
    #pragma unroll
    for (int mt = 0; mt < 8; ++mt) {
        int f = mt * 16 + g * 4;
        #pragma unroll
        for (int r = 0; r < 4; ++r) acc3[mt][r] = s_bc1[f + r];
    }
    #pragma unroll
    for (int kc = 0; kc < 4; ++kc)
        #pragma unroll
        for (int mt = 0; mt < 8; ++mt)
            acc3[mt] = __builtin_amdgcn_mfma_f32_16x16x32_bf16(A3[(mt * 4 + kc) * 64 + lane], B3[kc], acc3[mt], 0, 0, 0);

    // ---- coord weight dot + scatter (f32 atomics; only 3 ops/edge)
    float cwp = 0.f;
    #pragma unroll
    for (int mt = 0; mt < 8; ++mt) {
        int f = mt * 16 + g * 4;
        #pragma unroll
        for (int r = 0; r < 4; ++r)
            cwp += silu_f(acc3[mt][r]) * s_wc2[f + r];
    }
    cwp += __shfl_xor(cwp, 16, 64);
    cwp += __shfl_xor(cwp, 32, 64);
    float cw = cwp + bc2[0];
    if (g == 0) {
        atomicAdd(&coord_aggr[nc * 3 + 0], dx * cw);
        atomicAdd(&coord_aggr[nc * 3 + 1], dy * cw);
        atomicAdd(&coord_aggr[nc * 3 + 2], dz * cw);
    }
}

// ---------------------------------------------------------------------------
// Node kernel: transposed structure, 64 nodes/block; m read as f16.
// ---------------------------------------------------------------------------
__global__ __launch_bounds__(256) void egnn_node_mfma(
    const float* __restrict__ h, const float* __restrict__ x,
    const short* __restrict__ m16, const float* __restrict__ coord_aggr,
    const short* __restrict__ Wn1p, const float* __restrict__ bn1,
    const short* __restrict__ Wn2p, const float* __restrict__ bn2,
    float* __restrict__ h_out, float* __restrict__ x_out, int N)
{
    __shared__ short sStage[64 * 256];
    __shared__ float s_bn1[128], s_bn2[128];

    const int tid  = threadIdx.x;
    const int lane = tid & 63;
    const int w    = tid >> 6;
    const int l15  = lane & 15;
    const int g    = lane >> 4;
    const int n0   = blockIdx.x * 64;

    if (tid < 128) { s_bn1[tid] = bn1[tid]; s_bn2[tid] = bn2[tid]; }

    if (tid < 192) {
        int gi = n0 * 3 + tid;
        if (gi < 3 * N) x_out[gi] = x[gi] + coord_aggr[gi];
    }

    #pragma unroll
    for (int it = 0; it < 16; ++it) {
        int e = w + 4 * it;
        int q = lane;
        int node = min(n0 + e, N - 1);
        uint2 pk;
        if (q < 32) {
            float4 v = *(const float4*)&h[(size_t)node * HID + (size_t)q * 4];
            pk.x = cvt_pk(v.x, v.y);
            pk.y = cvt_pk(v.z, v.w);
        } else {
            uint2 hv = *(const uint2*)((const char*)m16 + (size_t)node * 256 + (size_t)(q & 31) * 8);
            const __fp16* hp = (const __fp16*)&hv;
            pk.x = cvt_pk((float)hp[0], (float)hp[1]);
            pk.y = cvt_pk((float)hp[2], (float)hp[3]);
        }
        *(uint2*)((char*)sStage + e * 512 + ((q * 8) ^ ((e & 7) << 4))) = pk;
    }
    __syncthreads();

    const int nloc = w * 16 + l15;
    const int node = n0 + nloc;
    const char* stageRow = (const char*)sStage + nloc * 512;
    const int sw = (nloc & 7) << 4;
    const bf16x8* A1 = (const bf16x8*)Wn1p;
    const bf16x8* A2 = (const bf16x8*)Wn2p;

    f32x4 acc[8];
    #pragma unroll
    for (int mt = 0; mt < 8; ++mt) {
        int f = mt * 16 + g * 4;
        #pragma unroll
        for (int r = 0; r < 4; ++r) acc[mt][r] = s_bn1[f + r];
    }
    #pragma unroll
    for (int kc = 0; kc < 8; ++kc) {
        int kb = kc * 64 + g * 8;
        uint2 lo = *(const uint2*)(stageRow + ((kb     ) ^ sw));
        uint2 hi = *(const uint2*)(stageRow + ((kb + 32) ^ sw));
        bf16x8 b; ((uint2*)&b)[0] = lo; ((uint2*)&b)[1] = hi;
        #pragma unroll
        for (int mt = 0; mt < 8; ++mt)
            acc[mt] = __builtin_amdgcn_mfma_f32_16x16x32_bf16(A1[(mt * 8 + kc) * 64 + lane], b, acc[mt], 0, 0, 0);
    }

    bf16x8 Bn[4];
    #pragma unroll
    for (int kc = 0; kc < 4; ++kc) {
        unsigned* d = (unsigned*)&Bn[kc];
        d[0] = cvt_pk(silu_f(acc[2 * kc][0]),     silu_f(acc[2 * kc][1]));
        d[1] = cvt_pk(silu_f(acc[2 * kc][2]),     silu_f(acc[2 * kc][3]));
        d[2] = cvt_pk(silu_f(acc[2 * kc + 1][0]), silu_f(acc[2 * kc + 1][1]));
        d[3] = cvt_pk(silu_f(acc[2 * kc + 1][2]), silu_f(acc[2 * kc + 1][3]));
    }

    f32x4 acc2[8];
    #pragma unroll
    for (int mt = 0; mt < 8; ++mt) {
        int f = mt * 16 + g * 4;
        #pragma unroll
        for (int r = 0; r < 4; ++r) acc2[mt][r] = s_bn2[f + r];
    }
    #pragma unroll
    for (int kc = 0; kc < 4; ++kc)
        #pragma unroll
        for (int mt = 0; mt < 8; ++mt)
            acc2[mt] = __builtin_amdgcn_mfma_f32_16x16x32_bf16(A2[(mt * 4 + kc) * 64 + lane], Bn[kc], acc2[mt], 0, 0, 0);

    if (node < N) {
        #pragma unroll
        for (int mt = 0; mt < 8; ++mt) {
            size_t base = (size_t)node * HID + mt * 16 + g * 4;
            float4 hres = *(const float4*)&h[base];
            float4 o;
            o.x = acc2[mt][0] + hres.x;
            o.y = acc2[mt][1] + hres.y;
            o.z = acc2[mt][2] + hres.z;
            o.w = acc2[mt][3] + hres.w;
            *(float4*)&h_out[base] = o;
        }
    }
}

extern "C" void kernel_launch(void* const* d_in, const int* in_sizes, int n_in,
                              void* d_out, int out_size, void* d_ws, size_t ws_size,
                              hipStream_t stream) {
    const float* h   = (const float*)d_in[0];
    const float* x   = (const float*)d_in[1];
    const int*   ei  = (const int*)d_in[2];
    const float* We1 = (const float*)d_in[3];
    const float* be1 = (const float*)d_in[4];
    const float* We2 = (const float*)d_in[5];
    const float* be2 = (const float*)d_in[6];
    const float* Wg  = (const float*)d_in[7];
    const float* bg  = (const float*)d_in[8];
    const float* Wn1 = (const float*)d_in[9];
    const float* bn1 = (const float*)d_in[10];
    const float* Wn2 = (const float*)d_in[11];
    const float* bn2 = (const float*)d_in[12];
    const float* Wc1 = (const float*)d_in[13];
    const float* bc1 = (const float*)d_in[14];
    const float* Wc2 = (const float*)d_in[15];
    const float* bc2 = (const float*)d_in[16];

    const int N = in_sizes[0] / HID;
    const int E = in_sizes[2] / 2;

    short* m16        = (short*)d_ws;                          // N*128 f16
    float* coord_aggr = (float*)(m16 + (size_t)N * HID);       // N*3 f32
    short* We1p       = (short*)(coord_aggr + (size_t)N * 3);  // 256*128 bf16
    short* We2p       = We1p + 256 * 128;                      // 128*128
    short* Wc1p       = We2p + 128 * 128;                      // 128*128
    short* Wn1p       = Wc1p + 128 * 128;                      // 256*128
    short* Wn2p       = Wn1p + 256 * 128;                      // 128*128

    (void)hipMemsetAsync(d_ws, 0, (size_t)N * (HID * 2 + 12), stream);

    float* h_out = (float*)d_out;
    float* x_out = h_out + (size_t)N * HID;

    egnn_prep<<<dim3(56), dim3(256), 0, stream>>>(
        We1, We2, Wc1, Wn1, Wn2, We1p, We2p, Wc1p, Wn1p, Wn2p);
    egnn_edge_mfma<<<dim3((E + 63) / 64), dim3(256), 0, stream>>>(
        h, x, ei, E, We1p, We1, be1, We2p, be2, Wg, bg, Wc1p, bc1, Wc2, bc2,
        m16, coord_aggr);
    egnn_node_mfma<<<dim3((N + 63) / 64), dim3(256), 0, stream>>>(
        h, x, m16, coord_aggr, Wn1p, bn1, Wn2p, bn2, h_out, x_out, N);
}